// Round 3
// baseline (122.598 us; speedup 1.0000x reference)
//
#include <hip/hip_runtime.h>
#include <hip/hip_bf16.h>
#include <stdint.h>

// SoftSplit = unfold(3x3,pad1)+linear == 3x3 same-conv Cin=64->Cout=96,
// out (8,16384,96) fp32. Round 3: two-pass.
//  Pass 1: NCHW fp32 -> padded NHWC bf16 xT[b][130][130][64] (halo zeroed),
//          transposed ONCE via 16KB LDS w/ XOR-swizzled 16B blocks.
//          W-prep folded into tail blocks.
//  Pass 2: conv. 512 thr = one output row (M=128). Staging = contiguous
//          49.9KB copy into padded-stride LDS (PSTR=36 dw/px, bank-uniform).
//          Barrier-free unrolled K-loop: ds_read_b128 A-frags + L2-hot
//          global B-frags + 16x16x32 bf16 MFMA. 2 blocks/CU.

typedef __bf16 bf16t;
typedef __bf16 bf16x8 __attribute__((ext_vector_type(8)));
typedef float  f32x4  __attribute__((ext_vector_type(4)));

#define CIN   64
#define COUT  96
#define HH    128
#define WW    128
#define KTOT  576
#define NCH   18
#define PSTR  36                 // dwords per pixel slot in pass-2 LDS (144 B, 16B-aligned)
#define XT_ROW_U4 1040           // uint4 per padded NHWC row: 130 px * 64 ch * 2B / 16

__device__ __forceinline__ int swz8(int px) { return ((px >> 2) & 7) ^ ((px & 3) << 1); }

__device__ __forceinline__ uint32_t pack2(float lo, float hi) {
    uint16_t a = __builtin_bit_cast(uint16_t, (__bf16)lo);
    uint16_t b = __builtin_bit_cast(uint16_t, (__bf16)hi);
    return ((uint32_t)b << 16) | (uint32_t)a;
}

// ---- Pass 1: blocks 0..1039 transpose one padded row; 1040..1047 prep W ----
__global__ __launch_bounds__(256) void pass1_kernel(
    const float* __restrict__ x, const float* __restrict__ W,
    bf16t* __restrict__ Wp, uint4* __restrict__ xT)
{
    const int tid = threadIdx.x;
    const int blk = blockIdx.x;

    if (blk >= 1040) {   // W (96 x 576, k = cin*9 + r) -> Wp[ch][n][cc], ch = r*2+half
        for (int idx = (blk - 1040) * 256 + tid; idx < NCH * COUT * 32; idx += 8 * 256) {
            int ch  = idx / (COUT * 32);
            int rem = idx - ch * (COUT * 32);
            int n = rem >> 5, cc = rem & 31;
            int r = ch >> 1, half = ch & 1;
            Wp[idx] = (bf16t)W[n * KTOT + (half * 32 + cc) * 9 + r];
        }
        return;
    }

    __shared__ __align__(16) uint32_t Ls[128 * 32];   // 16 KB: [px][32 dw] swizzled

    const int b = blk / 130;
    const int orow = blk - b * 130;
    uint4* xrow = xT + (size_t)(b * 130 + orow) * XT_ROW_U4;

    if (orow == 0 || orow == 129) {          // halo row: zeros
        for (int idx = tid; idx < XT_ROW_U4; idx += 256)
            xrow[idx] = (uint4){0u, 0u, 0u, 0u};
        return;
    }

    const int ii = orow - 1;
    const float* xb = x + (size_t)b * CIN * HH * WW + (size_t)ii * WW;

    #pragma unroll
    for (int it = 0; it < 4; ++it) {
        int g  = tid + 256 * it;             // 0..1023 = 32 ch-pairs * 32 j-groups
        int j0 = (g & 31) * 4;
        int cp = g >> 5;                     // channel pair 0..31
        const float* s0 = xb + (size_t)(2 * cp) * HH * WW + j0;
        float4 v0 = *(const float4*)s0;
        float4 v1 = *(const float4*)(s0 + HH * WW);
        float e0[4] = {v0.x, v0.y, v0.z, v0.w};
        float e1[4] = {v1.x, v1.y, v1.z, v1.w};
        #pragma unroll
        for (int u = 0; u < 4; ++u) {
            int px  = j0 + u;
            int cdw = (cp & 3) | ((((cp >> 2) ^ swz8(px)) & 7) << 2);
            Ls[px * 32 + cdw] = pack2(e0[u], e1[u]);
        }
    }
    __syncthreads();

    #pragma unroll
    for (int it = 0; it < 5; ++it) {
        int idx = tid + 256 * it;
        if (idx < XT_ROW_U4) {
            int p = idx >> 3, c = idx & 7;
            uint4 val;
            if (p == 0 || p == 129) {
                val = (uint4){0u, 0u, 0u, 0u};   // halo columns
            } else {
                int px = p - 1;
                val = *(const uint4*)&Ls[px * 32 + ((c ^ swz8(px)) & 7) * 4];
            }
            xrow[idx] = val;
        }
    }
}

// ---- Pass 2: conv. One output row per block (512 thr, 8 waves). ----
__global__ __launch_bounds__(512, 4) void conv_kernel(
    const uint4* __restrict__ xT, const bf16t* __restrict__ Wp,
    const float* __restrict__ bias, float* __restrict__ out)
{
    __shared__ __align__(16) uint32_t Xs[3 * 130 * PSTR];   // 56160 B

    const int tid  = threadIdx.x;
    const int lane = tid & 63;
    const int wave = tid >> 6;
    const int lrow = lane & 15;
    const int quad = lane >> 4;
    const int wn   = wave & 1;      // n-group: cols wn*48..+47 (3 n-tiles)
    const int wm   = wave >> 1;     // m-group: pixels wm*32..+31 (2 m-tiles)

    const int bb = blockIdx.x & 7;     // batch -> XCD-local
    const int oi = blockIdx.x >> 3;    // output row 0..127

    // stage 3 padded rows (contiguous in xT) into padded-stride LDS
    const uint4* src = xT + (size_t)(bb * 130 + oi) * XT_ROW_U4;
    #pragma unroll
    for (int it = 0; it < 7; ++it) {
        int s = tid + 512 * it;
        if (s < 3 * XT_ROW_U4) {
            int row = s / XT_ROW_U4;
            int rem = s - row * XT_ROW_U4;
            int p = rem >> 3, c = rem & 7;
            *(uint4*)&Xs[(row * 130 + p) * PSTR + c * 4] = src[s];
        }
    }
    __syncthreads();

    f32x4 acc[2][3];
    #pragma unroll
    for (int a = 0; a < 2; ++a)
        #pragma unroll
        for (int nt = 0; nt < 3; ++nt)
            acc[a][nt] = (f32x4){0.f, 0.f, 0.f, 0.f};

    const bf16t* wp_n = Wp + (size_t)(wn * 48 + lrow) * 32 + quad * 8;
    const int m0 = wm * 32 + lrow;

    #pragma unroll 1
    for (int ki = 0; ki < 3; ++ki) {
        #pragma unroll 1
        for (int kj = 0; kj < 3; ++kj) {
            #pragma unroll
            for (int half = 0; half < 2; ++half) {
                const int ch = (ki * 3 + kj) * 2 + half;
                bf16x8 bfr[3];
                #pragma unroll
                for (int nt = 0; nt < 3; ++nt)
                    bfr[nt] = *(const bf16x8*)(wp_n + (size_t)ch * COUT * 32 + nt * 512);
                bf16x8 afr[2];
                #pragma unroll
                for (int a = 0; a < 2; ++a) {
                    int dw = (ki * 130 + m0 + a * 16 + kj) * PSTR + half * 16 + quad * 4;
                    afr[a] = *(const bf16x8*)&Xs[dw];
                }
                #pragma unroll
                for (int a = 0; a < 2; ++a)
                    #pragma unroll
                    for (int nt = 0; nt < 3; ++nt)
                        acc[a][nt] = __builtin_amdgcn_mfma_f32_16x16x32_bf16(
                            afr[a], bfr[nt], acc[a][nt], 0, 0, 0);
            }
        }
    }

    // epilogue: D col=lane&15 (c2), row=quad*4+reg (pixel)
    float bv[3];
    #pragma unroll
    for (int nt = 0; nt < 3; ++nt) bv[nt] = bias[wn * 48 + nt * 16 + lrow];

    float* outp = out + ((size_t)bb * 16384 + (size_t)oi * 128) * COUT + wn * 48;
    #pragma unroll
    for (int a = 0; a < 2; ++a) {
        #pragma unroll
        for (int rg = 0; rg < 4; ++rg) {
            int m = wm * 32 + a * 16 + quad * 4 + rg;
            float* rowp = outp + (size_t)m * COUT;
            #pragma unroll
            for (int nt = 0; nt < 3; ++nt)
                rowp[nt * 16 + lrow] = acc[a][nt][rg] + bv[nt];
        }
    }
}

extern "C" void kernel_launch(void* const* d_in, const int* in_sizes, int n_in,
                              void* d_out, int out_size, void* d_ws, size_t ws_size,
                              hipStream_t stream) {
    const float* x    = (const float*)d_in[0];   // (8,64,128,128)
    const float* W    = (const float*)d_in[1];   // (96,576)
    const float* bias = (const float*)d_in[2];   // (96,)
    float* out = (float*)d_out;                  // (8,16384,96)

    bf16t* Wp = (bf16t*)d_ws;                        // 110592 B
    uint4* xT = (uint4*)((char*)d_ws + 131072);      // 17.3 MB padded NHWC bf16

    hipLaunchKernelGGL(pass1_kernel, dim3(1048), dim3(256), 0, stream, x, W, Wp, xT);
    hipLaunchKernelGGL(conv_kernel,  dim3(8 * HH), dim3(512), 0, stream, xT, Wp, bias, out);
}

// Round 4
// 119.141 us; speedup vs baseline: 1.0290x; 1.0290x over previous
//
#include <hip/hip_runtime.h>
#include <hip/hip_bf16.h>
#include <stdint.h>

// SoftSplit = unfold(3x3,pad1)+linear == 3x3 same-conv Cin=64->Cout=96,
// out (8,16384,96) fp32. Round 4: two-pass + software-pipelined B preload.
//  Pass 1: NCHW fp32 -> padded NHWC bf16 xT[b][130][130][64] (halo zeroed),
//          transposed once via 16KB LDS; W-prep in tail blocks. (unchanged)
//  Pass 2: conv, 512 thr = one output row (M=128), wave = 2 m-tiles x 3 n-tiles.
//          B fragments double-buffered in VGPRs, 3 chunks/phase, preload
//          issued a full phase ahead (phase 0 before the staging barrier) so
//          L2 latency (~200cyc) is never on the critical path. K-loop has
//          zero same-iteration global dependencies and no barriers.

typedef __bf16 bf16t;
typedef __bf16 bf16x8 __attribute__((ext_vector_type(8)));
typedef float  f32x4  __attribute__((ext_vector_type(4)));

#define CIN   64
#define COUT  96
#define HH    128
#define WW    128
#define KTOT  576
#define NCH   18
#define PSTR  36                 // dwords per pixel slot in conv LDS (144 B)
#define XT_ROW_U4 1040           // uint4 per padded NHWC row: 130*64*2B/16

__device__ __forceinline__ int swz8(int px) { return ((px >> 2) & 7) ^ ((px & 3) << 1); }

__device__ __forceinline__ uint32_t pack2(float lo, float hi) {
    uint16_t a = __builtin_bit_cast(uint16_t, (__bf16)lo);
    uint16_t b = __builtin_bit_cast(uint16_t, (__bf16)hi);
    return ((uint32_t)b << 16) | (uint32_t)a;
}

// ---- Pass 1: blocks 0..1039 transpose one padded row; 1040..1047 prep W ----
__global__ __launch_bounds__(256) void pass1_kernel(
    const float* __restrict__ x, const float* __restrict__ W,
    bf16t* __restrict__ Wp, uint4* __restrict__ xT)
{
    const int tid = threadIdx.x;
    const int blk = blockIdx.x;

    if (blk >= 1040) {   // W (96 x 576, k = cin*9 + r) -> Wp[ch][n][cc], ch = r*2+half
        for (int idx = (blk - 1040) * 256 + tid; idx < NCH * COUT * 32; idx += 8 * 256) {
            int ch  = idx / (COUT * 32);
            int rem = idx - ch * (COUT * 32);
            int n = rem >> 5, cc = rem & 31;
            int r = ch >> 1, half = ch & 1;
            Wp[idx] = (bf16t)W[n * KTOT + (half * 32 + cc) * 9 + r];
        }
        return;
    }

    __shared__ __align__(16) uint32_t Ls[128 * 32];   // 16 KB: [px][32 dw] swizzled

    const int b = blk / 130;
    const int orow = blk - b * 130;
    uint4* xrow = xT + (size_t)(b * 130 + orow) * XT_ROW_U4;

    if (orow == 0 || orow == 129) {          // halo row: zeros
        for (int idx = tid; idx < XT_ROW_U4; idx += 256)
            xrow[idx] = (uint4){0u, 0u, 0u, 0u};
        return;
    }

    const int ii = orow - 1;
    const float* xb = x + (size_t)b * CIN * HH * WW + (size_t)ii * WW;

    #pragma unroll
    for (int it = 0; it < 4; ++it) {
        int g  = tid + 256 * it;             // 0..1023 = 32 ch-pairs * 32 j-groups
        int j0 = (g & 31) * 4;
        int cp = g >> 5;
        const float* s0 = xb + (size_t)(2 * cp) * HH * WW + j0;
        float4 v0 = *(const float4*)s0;
        float4 v1 = *(const float4*)(s0 + HH * WW);
        float e0[4] = {v0.x, v0.y, v0.z, v0.w};
        float e1[4] = {v1.x, v1.y, v1.z, v1.w};
        #pragma unroll
        for (int u = 0; u < 4; ++u) {
            int px  = j0 + u;
            int cdw = (cp & 3) | ((((cp >> 2) ^ swz8(px)) & 7) << 2);
            Ls[px * 32 + cdw] = pack2(e0[u], e1[u]);
        }
    }
    __syncthreads();

    #pragma unroll
    for (int it = 0; it < 5; ++it) {
        int idx = tid + 256 * it;
        if (idx < XT_ROW_U4) {
            int p = idx >> 3, c = idx & 7;
            uint4 val;
            if (p == 0 || p == 129) {
                val = (uint4){0u, 0u, 0u, 0u};
            } else {
                int px = p - 1;
                val = *(const uint4*)&Ls[px * 32 + ((c ^ swz8(px)) & 7) * 4];
            }
            xrow[idx] = val;
        }
    }
}

// ---- Pass 2: conv, pipelined B preload ----
__global__ __launch_bounds__(512, 4) void conv_kernel(
    const uint4* __restrict__ xT, const bf16t* __restrict__ Wp,
    const float* __restrict__ bias, float* __restrict__ out)
{
    __shared__ __align__(16) uint32_t Xs[3 * 130 * PSTR];   // 56160 B

    const int tid  = threadIdx.x;
    const int lane = tid & 63;
    const int wave = tid >> 6;
    const int lrow = lane & 15;
    const int quad = lane >> 4;
    const int wn   = wave & 1;      // n-group: cols wn*48..+47 (3 n-tiles)
    const int wm   = wave >> 1;     // m-group: pixels wm*32..+31 (2 m-tiles)

    const int bb = blockIdx.x & 7;     // batch -> XCD-local
    const int oi = blockIdx.x >> 3;    // output row 0..127

    const bf16t* wp_n = Wp + (size_t)(wn * 48 + lrow) * 32 + quad * 8;

    // ---- issue phase-0 B loads FIRST (latency hides behind staging) ----
    bf16x8 bcur[9], bnxt[9];
    #pragma unroll
    for (int c = 0; c < 3; ++c)
        #pragma unroll
        for (int nt = 0; nt < 3; ++nt)
            bcur[c * 3 + nt] = *(const bf16x8*)(wp_n + (size_t)c * 3072 + nt * 512);

    // ---- stage 3 padded rows (contiguous in xT) into padded-stride LDS ----
    const uint4* src = xT + (size_t)(bb * 130 + oi) * XT_ROW_U4;
    #pragma unroll
    for (int it = 0; it < 7; ++it) {
        int s = tid + 512 * it;
        if (s < 3 * XT_ROW_U4) {
            int row = s / XT_ROW_U4;
            int rem = s - row * XT_ROW_U4;
            int p = rem >> 3, c = rem & 7;
            *(uint4*)&Xs[(row * 130 + p) * PSTR + c * 4] = src[s];
        }
    }
    __syncthreads();

    f32x4 acc[2][3];
    #pragma unroll
    for (int a = 0; a < 2; ++a)
        #pragma unroll
        for (int nt = 0; nt < 3; ++nt)
            acc[a][nt] = (f32x4){0.f, 0.f, 0.f, 0.f};

    const int m0 = wm * 32 + lrow;

    // ---- 6 phases x 3 chunks, fully unrolled, B always one phase ahead ----
    #pragma unroll
    for (int ph = 0; ph < 6; ++ph) {
        if (ph < 5) {
            #pragma unroll
            for (int c = 0; c < 3; ++c)
                #pragma unroll
                for (int nt = 0; nt < 3; ++nt)
                    bnxt[c * 3 + nt] =
                        *(const bf16x8*)(wp_n + (size_t)((ph + 1) * 3 + c) * 3072 + nt * 512);
        }
        #pragma unroll
        for (int c = 0; c < 3; ++c) {
            const int ch = ph * 3 + c;
            const int ki = ch / 6, kj = (ch % 6) >> 1, half = ch & 1;
            bf16x8 a0 = *(const bf16x8*)&Xs[(ki * 130 + m0 + kj) * PSTR + half * 16 + quad * 4];
            bf16x8 a1 = *(const bf16x8*)&Xs[(ki * 130 + m0 + 16 + kj) * PSTR + half * 16 + quad * 4];
            #pragma unroll
            for (int nt = 0; nt < 3; ++nt) {
                acc[0][nt] = __builtin_amdgcn_mfma_f32_16x16x32_bf16(a0, bcur[c * 3 + nt], acc[0][nt], 0, 0, 0);
                acc[1][nt] = __builtin_amdgcn_mfma_f32_16x16x32_bf16(a1, bcur[c * 3 + nt], acc[1][nt], 0, 0, 0);
            }
        }
        #pragma unroll
        for (int i = 0; i < 9; ++i) bcur[i] = bnxt[i];   // elided by SSA under full unroll
    }

    // ---- epilogue: D col=lane&15 (c2), row=quad*4+reg (pixel) ----
    float bv[3];
    #pragma unroll
    for (int nt = 0; nt < 3; ++nt) bv[nt] = bias[wn * 48 + nt * 16 + lrow];

    float* outp = out + ((size_t)bb * 16384 + (size_t)oi * 128) * COUT + wn * 48;
    #pragma unroll
    for (int a = 0; a < 2; ++a) {
        #pragma unroll
        for (int rg = 0; rg < 4; ++rg) {
            int m = wm * 32 + a * 16 + quad * 4 + rg;
            float* rowp = outp + (size_t)m * COUT;
            #pragma unroll
            for (int nt = 0; nt < 3; ++nt)
                rowp[nt * 16 + lrow] = acc[a][nt][rg] + bv[nt];
        }
    }
}

extern "C" void kernel_launch(void* const* d_in, const int* in_sizes, int n_in,
                              void* d_out, int out_size, void* d_ws, size_t ws_size,
                              hipStream_t stream) {
    const float* x    = (const float*)d_in[0];   // (8,64,128,128)
    const float* W    = (const float*)d_in[1];   // (96,576)
    const float* bias = (const float*)d_in[2];   // (96,)
    float* out = (float*)d_out;                  // (8,16384,96)

    bf16t* Wp = (bf16t*)d_ws;                        // 110592 B
    uint4* xT = (uint4*)((char*)d_ws + 131072);      // 17.3 MB padded NHWC bf16

    hipLaunchKernelGGL(pass1_kernel, dim3(1048), dim3(256), 0, stream, x, W, Wp, xT);
    hipLaunchKernelGGL(conv_kernel,  dim3(8 * HH), dim3(512), 0, stream, xT, Wp, bias, out);
}

// Round 5
// 109.945 us; speedup vs baseline: 1.1151x; 1.0836x over previous
//
#include <hip/hip_runtime.h>
#include <hip/hip_bf16.h>
#include <stdint.h>

// SoftSplit = unfold(3x3,pad1)+linear == 3x3 same-conv Cin=64->Cout=96,
// out (8,16384,96) fp32. Round 5: single fused pass, M=256 per block.
//  - 512 thr/block, block = 2 output rows of one batch. Stages 4 input rows
//    NCHW fp32 -> LDS bf16 NHWC (xor-swizzled 16B blocks, R2-verified),
//    66.5 KB LDS -> 2 blocks/CU. No intermediate xT, no second pass.
//  - Waves: 2 n-groups x 4 m-groups; each wave 4 m-tiles x 3 n-tiles.
//  - B fragments register-preloaded 1 chunk ahead (chunk 0 before staging);
//    barrier-free fully-unrolled 18-chunk K-loop.
//  - blockIdx&7 = batch -> XCD-local input slab (4.2 MB ~ L2).

typedef __bf16 bf16t;
typedef __bf16 bf16x8 __attribute__((ext_vector_type(8)));
typedef float  f32x4  __attribute__((ext_vector_type(4)));

#define CIN   64
#define COUT  96
#define HH    128
#define WW    128
#define KTOT  576
#define NCH   18
#define XROW  (130 * 32)          // dwords per staged row slab
#define XTOT  (4 * XROW)          // 16640 dw = 66560 B

__device__ __forceinline__ int swz8(int px) { return ((px >> 2) & 7) ^ ((px & 3) << 1); }

__device__ __forceinline__ uint32_t pack2(float lo, float hi) {
    uint16_t a = __builtin_bit_cast(uint16_t, (__bf16)lo);
    uint16_t b = __builtin_bit_cast(uint16_t, (__bf16)hi);
    return ((uint32_t)b << 16) | (uint32_t)a;
}

// W (96 x 576 fp32, k = cin*9 + r) -> Wp[ch][n][cc] bf16, ch = r*2+half
__global__ __launch_bounds__(256) void prep_w_kernel(
    const float* __restrict__ W, bf16t* __restrict__ Wp)
{
    int idx = blockIdx.x * 256 + threadIdx.x;
    if (idx >= NCH * COUT * 32) return;
    int ch  = idx / (COUT * 32);
    int rem = idx - ch * (COUT * 32);
    int n = rem >> 5, cc = rem & 31;
    int r = ch >> 1, half = ch & 1;
    Wp[idx] = (bf16t)W[n * KTOT + (half * 32 + cc) * 9 + r];
}

__global__ __launch_bounds__(512, 4) void conv_kernel(
    const float* __restrict__ x, const bf16t* __restrict__ Wp,
    const float* __restrict__ bias, float* __restrict__ out)
{
    __shared__ __align__(16) uint32_t Xs[XTOT];

    const int tid  = threadIdx.x;
    const int lane = tid & 63;
    const int wave = tid >> 6;
    const int lrow = lane & 15;
    const int quad = lane >> 4;
    const int wn   = wave & 1;       // n-group: cols wn*48..+47 (3 n-tiles)
    const int wm   = wave >> 1;      // m-group: pixels wm*64..+63 (4 m-tiles)

    const int bb  = blockIdx.x & 7;  // batch -> XCD-local
    const int orp = blockIdx.x >> 3; // output row-pair 0..63

    const bf16t* wp_n = Wp + (size_t)(wn * 48 + lrow) * 32 + quad * 8;

    // ---- issue chunk-0 B loads first (latency hides behind staging) ----
    bf16x8 bcur[3], bnxt[3];
    #pragma unroll
    for (int nt = 0; nt < 3; ++nt)
        bcur[nt] = *(const bf16x8*)(wp_n + nt * 512);

    // ---- zero LDS (halo rows/cols must read 0) ----
    uint4* X4 = (uint4*)Xs;
    #pragma unroll
    for (int i = 0; i < 9; ++i) {
        int idx = tid + 512 * i;
        if (idx < XTOT / 4) X4[idx] = (uint4){0u, 0u, 0u, 0u};
    }
    __syncthreads();

    // ---- stage 4 input rows: NCHW fp32 -> swizzled NHWC bf16 ----
    const float* xb = x + (size_t)bb * CIN * HH * WW;
    #pragma unroll
    for (int it = 0; it < 8; ++it) {
        int g  = tid + 512 * it;          // 0..4095 = 4 rows * 32 cp * 32 jg
        int j0 = (g & 31) * 4;
        int cp = (g >> 5) & 31;
        int rh = g >> 10;                 // 0..3
        int ii = orp * 2 - 1 + rh;
        if ((unsigned)ii < (unsigned)HH) {
            const float* s0 = xb + ((size_t)(2 * cp) * HH + ii) * WW + j0;
            float4 v0 = *(const float4*)s0;
            float4 v1 = *(const float4*)(s0 + HH * WW);
            float e0[4] = {v0.x, v0.y, v0.z, v0.w};
            float e1[4] = {v1.x, v1.y, v1.z, v1.w};
            #pragma unroll
            for (int u = 0; u < 4; ++u) {
                int px  = 1 + j0 + u;
                int cdw = (cp & 3) | ((((cp >> 2) ^ swz8(px)) & 7) << 2);
                Xs[rh * XROW + px * 32 + cdw] = pack2(e0[u], e1[u]);
            }
        }
    }
    __syncthreads();

    // ---- barrier-free K-loop: 18 chunks, B one chunk ahead ----
    f32x4 acc[4][3];
    #pragma unroll
    for (int a = 0; a < 4; ++a)
        #pragma unroll
        for (int nt = 0; nt < 3; ++nt)
            acc[a][nt] = (f32x4){0.f, 0.f, 0.f, 0.f};

    #pragma unroll
    for (int ch = 0; ch < NCH; ++ch) {
        if (ch < NCH - 1) {
            #pragma unroll
            for (int nt = 0; nt < 3; ++nt)
                bnxt[nt] = *(const bf16x8*)(wp_n + (size_t)(ch + 1) * 3072 + nt * 512);
        }
        const int ki = ch / 6, kj = (ch % 6) >> 1, half = ch & 1;
        bf16x8 afr[4];
        #pragma unroll
        for (int a = 0; a < 4; ++a) {
            int mb   = wm * 64 + a * 16;
            int slab = (mb >> 7) + ki;
            int p    = (mb & 127) + lrow + kj;
            int blk  = (half * 4 + quad) ^ swz8(p);
            afr[a] = *(const bf16x8*)&Xs[slab * XROW + p * 32 + blk * 4];
        }
        #pragma unroll
        for (int a = 0; a < 4; ++a)
            #pragma unroll
            for (int nt = 0; nt < 3; ++nt)
                acc[a][nt] = __builtin_amdgcn_mfma_f32_16x16x32_bf16(
                    afr[a], bcur[nt], acc[a][nt], 0, 0, 0);
        #pragma unroll
        for (int nt = 0; nt < 3; ++nt) bcur[nt] = bnxt[nt];
    }

    // ---- epilogue: D col=lane&15 (c2), row=quad*4+reg (pixel) ----
    float bv[3];
    #pragma unroll
    for (int nt = 0; nt < 3; ++nt) bv[nt] = bias[wn * 48 + nt * 16 + lrow];

    float* outp = out + ((size_t)bb * 16384 + (size_t)orp * 256) * COUT + wn * 48;
    #pragma unroll
    for (int a = 0; a < 4; ++a) {
        #pragma unroll
        for (int rg = 0; rg < 4; ++rg) {
            int mm = wm * 64 + a * 16 + quad * 4 + rg;   // 0..255
            float* rowp = outp + (size_t)mm * COUT;
            #pragma unroll
            for (int nt = 0; nt < 3; ++nt)
                rowp[nt * 16 + lrow] = acc[a][nt][rg] + bv[nt];
        }
    }
}

extern "C" void kernel_launch(void* const* d_in, const int* in_sizes, int n_in,
                              void* d_out, int out_size, void* d_ws, size_t ws_size,
                              hipStream_t stream) {
    const float* x    = (const float*)d_in[0];   // (8,64,128,128)
    const float* W    = (const float*)d_in[1];   // (96,576)
    const float* bias = (const float*)d_in[2];   // (96,)
    float* out = (float*)d_out;                  // (8,16384,96)
    bf16t* Wp  = (bf16t*)d_ws;                   // 110592 B scratch

    hipLaunchKernelGGL(prep_w_kernel, dim3((NCH * COUT * 32 + 255) / 256), dim3(256), 0, stream,
                       W, Wp);
    hipLaunchKernelGGL(conv_kernel, dim3(512), dim3(512), 0, stream,
                       x, Wp, bias, out);
}